// Round 9
// baseline (194.527 us; speedup 1.0000x reference)
//
#include <hip/hip_runtime.h>
#include <stdint.h>

// AffineCoupling: B=65536 rows, DIM=128, D_IN=64, HID=512, 2 extra hidden layers.
// Fused bf16-MFMA, 32x32x16. 128 rows/block (512 blocks), 8 waves, 1 block/CU
// (136KB LDS), launch_bounds(512,2) -> 256 unified regs/wave.
// Wave owns 64 neurons (nt=2) x 128 rows (rt=4): per K=16 step 2 A + 4 B loads
// feed 8 MFMAs (2x the arithmetic intensity of R8's RPB=64 -> halves L2 weight
// traffic, the structural cap). A/B single-step-ahead prefetch with explicit
// 4-step ping-pong naming (no rotation movs); bounded unroll windows (R7
// lesson: unbounded hoisting => scratch spill).
// Weights repacked k-major-tiled in d_ws: elem(m,k) -> (m>>5)*tsz + (k>>3)*256
// + (m&31)*8 + (k&7): an A-frag is ONE contiguous 1KB wave-load.
// LDS h k-major tiled: h[row][n] at byte (n>>3)*2048 + row*16 + (n&7)*2.
// Final (64-neuron) layers: split nt-full x row-quarter x k-half across 8
// waves + LDS partial reduce. log_s stashed in out's z2 region (same-thread RAW).

#define NROWS 65536
#define RPB   128
#define NBLK  (NROWS / RPB)

// bf16 weight scratch layout (element offsets in d_ws)
#define OFF_S_WIN   0
#define OFF_S_WHID  32768
#define OFF_S_WOUT  557056
#define OFF_T_WIN   589824
#define OFF_T_WHID  622592
#define OFF_T_WOUT  1146880
#define W_ELEMS     1179648

typedef __attribute__((ext_vector_type(8)))  short short8;
typedef __attribute__((ext_vector_type(4)))  float f32x4;
typedef __attribute__((ext_vector_type(16))) float f32x16;

__device__ __forceinline__ uint32_t f2bf1(float f) {
  uint32_t u = __float_as_uint(f);
  return (u + 0x7fffu + ((u >> 16) & 1u)) >> 16;   // RNE
}
__device__ __forceinline__ uint32_t pk2bf(float a, float b) {
  return f2bf1(a) | (f2bf1(b) << 16);
}

// ---------------- weight fp32 -> bf16 + k-major repack prologue ----------------
__global__ void cvt_weights(const float* __restrict__ sWin, const float* __restrict__ sWhid,
                            const float* __restrict__ sWout, const float* __restrict__ tWin,
                            const float* __restrict__ tWhid, const float* __restrict__ tWout,
                            uint16_t* __restrict__ wbf) {
  int g = blockIdx.x * blockDim.x + threadIdx.x;
  int e = g * 4;
  if (e >= W_ELEMS) return;
  const float* src; int off, base; bool k64;
  if      (e < OFF_S_WHID) { src = sWin;  off = e;              base = OFF_S_WIN;  k64 = true; }
  else if (e < OFF_S_WOUT) { src = sWhid; off = e - OFF_S_WHID; base = OFF_S_WHID; k64 = false; }
  else if (e < OFF_T_WIN)  { src = sWout; off = e - OFF_S_WOUT; base = OFF_S_WOUT; k64 = false; }
  else if (e < OFF_T_WHID) { src = tWin;  off = e - OFF_T_WIN;  base = OFF_T_WIN;  k64 = true; }
  else if (e < OFF_T_WOUT) { src = tWhid; off = e - OFF_T_WHID; base = OFF_T_WHID; k64 = false; }
  else                     { src = tWout; off = e - OFF_T_WOUT; base = OFF_T_WOUT; k64 = false; }
  int m, k, tsz;
  if (k64) { m = off >> 6; k = off & 63;  tsz = 2048;  }
  else     { m = off >> 9; k = off & 511; tsz = 16384; }
  int dest = base + (m >> 5) * tsz + (k >> 3) * 256 + (m & 31) * 8 + (k & 7);
  f32x4 v = *(const f32x4*)(src + off);
  uint2 r; r.x = pk2bf(v.x, v.y); r.y = pk2bf(v.z, v.w);
  *(uint2*)(wbf + dest) = r;
}

// ---------------- A-frag loader ----------------
template<bool BF>
__device__ __forceinline__ short8 ldW(const uint16_t* __restrict__ wb,
                                      const float* __restrict__ wf, int pidx, int oidx) {
  if (BF) {
    return *(const short8*)(wb + pidx);
  } else {
    f32x4 x = *(const f32x4*)(wf + oidx);
    f32x4 y = *(const f32x4*)(wf + oidx + 4);
    short8 r;
    r[0] = (short)f2bf1(x.x); r[1] = (short)f2bf1(x.y);
    r[2] = (short)f2bf1(x.z); r[3] = (short)f2bf1(x.w);
    r[4] = (short)f2bf1(y.x); r[5] = (short)f2bf1(y.y);
    r[6] = (short)f2bf1(y.z); r[7] = (short)f2bf1(y.w);
    return r;
  }
}

#define MFMA32(a, b, c) __builtin_amdgcn_mfma_f32_32x32x16_bf16(a, b, c, 0, 0, 0)

// ---------------- epilogue: bias + relu + pack + k-major LDS store ----------------
// C layout (32x32): col=lane&31=batch row; m=(reg&3)+8*(reg>>2)+4*(lane>>5).
__device__ __forceinline__ void store_h32(f32x16 acc[2][4], const float* __restrict__ bias,
                                          uint16_t* hdst, int wave, int lane) {
  const int l31 = lane & 31, lh = lane >> 5;
  __syncthreads();   // all waves done READING h (h is read+written in place)
  char* wp = (char*)hdst + wave * 16384 + l31 * 16 + lh * 8;
  #pragma unroll
  for (int nt = 0; nt < 2; ++nt) {
    #pragma unroll
    for (int q = 0; q < 4; ++q) {
      const int m0 = wave * 64 + nt * 32 + q * 8 + lh * 4;
      f32x4 bv = *(const f32x4*)(bias + m0);
      #pragma unroll
      for (int rt = 0; rt < 4; ++rt) {
        float v0 = acc[nt][rt][q * 4 + 0] + bv.x;
        float v1 = acc[nt][rt][q * 4 + 1] + bv.y;
        float v2 = acc[nt][rt][q * 4 + 2] + bv.z;
        float v3 = acc[nt][rt][q * 4 + 3] + bv.w;
        uint2 p;
        p.x = pk2bf(fmaxf(v0, 0.f), fmaxf(v1, 0.f));
        p.y = pk2bf(fmaxf(v2, 0.f), fmaxf(v3, 0.f));
        *(uint2*)(wp + nt * 8192 + q * 2048 + rt * 512) = p;
      }
    }
  }
  __syncthreads();
}

// ---------------- layer 1: h = relu(W @ z1^T + b), K=64, B built from global z ----------------
template<bool BF>
__device__ __forceinline__ void dense_in(
    const uint16_t* __restrict__ wb, const float* __restrict__ wf,
    const float* __restrict__ bias, const float* __restrict__ z, long rowbase,
    uint16_t* hdst, int wave, int lane) {
  const int l31 = lane & 31, lh = lane >> 5;
  f32x16 acc[2][4];
  #pragma unroll
  for (int i = 0; i < 2; ++i)
    #pragma unroll
    for (int j = 0; j < 4; ++j) acc[i][j] = (f32x16)0.f;
  #pragma unroll 1
  for (int ks = 0; ks < 4; ++ks) {
    short8 a0 = ldW<BF>(wb, wf, (wave * 2 + 0) * 2048 + (2 * ks + lh) * 256 + l31 * 8,
                        (wave * 64 + 0 + l31) * 64 + ks * 16 + lh * 8);
    short8 a1 = ldW<BF>(wb, wf, (wave * 2 + 1) * 2048 + (2 * ks + lh) * 256 + l31 * 8,
                        (wave * 64 + 32 + l31) * 64 + ks * 16 + lh * 8);
    #pragma unroll
    for (int rt = 0; rt < 4; ++rt) {
      const float* zp = z + (rowbase + rt * 32 + l31) * 128 + ks * 16 + lh * 8;
      f32x4 u = *(const f32x4*)zp;
      f32x4 v = *(const f32x4*)(zp + 4);
      short8 b;
      b[0] = (short)f2bf1(u.x); b[1] = (short)f2bf1(u.y);
      b[2] = (short)f2bf1(u.z); b[3] = (short)f2bf1(u.w);
      b[4] = (short)f2bf1(v.x); b[5] = (short)f2bf1(v.y);
      b[6] = (short)f2bf1(v.z); b[7] = (short)f2bf1(v.w);
      acc[0][rt] = MFMA32(a0, b, acc[0][rt]);
      acc[1][rt] = MFMA32(a1, b, acc[1][rt]);
    }
  }
  store_h32(acc, bias, hdst, wave, lane);
}

// ---------------- hidden layer: h = relu(W @ h^T + b), K=512 ----------------
// 32 K=16 steps as 8 chunks x 4; A and B one-step-ahead via explicit ping-pong
// naming (no copy movs). All LDS/global offsets: chunk base + static immediate.
// HSTEP: issue next-step loads (AOFF/BOFF rel. to chunk bases), then 8 MFMAs.
#define HSTEP(AC0, AC1, BC0, BC1, BC2, BC3, AN0, AN1, BN0, BN1, BN2, BN3, AOFF, BOFF) \
  AN0 = ldW<BF>(wb, wf, wpc + (AOFF),         woc + (AOFF) / 32);                     \
  AN1 = ldW<BF>(wb, wf, wpc + 16384 + (AOFF), woc + 16384 + (AOFF) / 32);             \
  BN0 = *(const short8*)(bc + (BOFF));                                                \
  BN1 = *(const short8*)(bc + (BOFF) + 512);                                          \
  BN2 = *(const short8*)(bc + (BOFF) + 1024);                                         \
  BN3 = *(const short8*)(bc + (BOFF) + 1536);                                         \
  __builtin_amdgcn_s_setprio(1);                                                      \
  acc[0][0] = MFMA32(AC0, BC0, acc[0][0]);                                            \
  acc[0][1] = MFMA32(AC0, BC1, acc[0][1]);                                            \
  acc[0][2] = MFMA32(AC0, BC2, acc[0][2]);                                            \
  acc[0][3] = MFMA32(AC0, BC3, acc[0][3]);                                            \
  acc[1][0] = MFMA32(AC1, BC0, acc[1][0]);                                            \
  acc[1][1] = MFMA32(AC1, BC1, acc[1][1]);                                            \
  acc[1][2] = MFMA32(AC1, BC2, acc[1][2]);                                            \
  acc[1][3] = MFMA32(AC1, BC3, acc[1][3]);                                            \
  __builtin_amdgcn_s_setprio(0);

template<bool BF>
__device__ __forceinline__ void dense_relu512(
    const uint16_t* __restrict__ wb, const float* __restrict__ wf,
    const float* __restrict__ bias, uint16_t* hbuf, int wave, int lane) {
  const int l31 = lane & 31, lh = lane >> 5;
  f32x16 acc[2][4];
  #pragma unroll
  for (int i = 0; i < 2; ++i)
    #pragma unroll
    for (int j = 0; j < 4; ++j) acc[i][j] = (f32x16)0.f;
  const int wbaseP = wave * 2 * 16384 + lh * 256 + l31 * 8;   // + nt*16384 + ks*512
  const int wbaseO = (wave * 64 + l31) * 512 + lh * 8;        // + nt*32*512 + ks*16
  const char* bb = (const char*)hbuf + lh * 2048 + l31 * 16;  // + ks*4096 + rt*512

  short8 aC0, aC1, aN0, aN1, bC0, bC1, bC2, bC3, bN0, bN1, bN2, bN3;
  aC0 = ldW<BF>(wb, wf, wbaseP, wbaseO);
  aC1 = ldW<BF>(wb, wf, wbaseP + 16384, wbaseO + 16384);
  bC0 = *(const short8*)(bb);
  bC1 = *(const short8*)(bb + 512);
  bC2 = *(const short8*)(bb + 1024);
  bC3 = *(const short8*)(bb + 1536);

  #pragma unroll 1
  for (int c = 0; c < 7; ++c) {
    const int   wpc = wbaseP + c * 2048;
    const int   woc = wbaseO + c * 64;
    const char* bc  = bb + c * 16384;
    HSTEP(aC0, aC1, bC0, bC1, bC2, bC3, aN0, aN1, bN0, bN1, bN2, bN3, 1 * 512, 1 * 4096)
    HSTEP(aN0, aN1, bN0, bN1, bN2, bN3, aC0, aC1, bC0, bC1, bC2, bC3, 2 * 512, 2 * 4096)
    HSTEP(aC0, aC1, bC0, bC1, bC2, bC3, aN0, aN1, bN0, bN1, bN2, bN3, 3 * 512, 3 * 4096)
    HSTEP(aN0, aN1, bN0, bN1, bN2, bN3, aC0, aC1, bC0, bC1, bC2, bC3, 4 * 512, 4 * 4096)
  }
  {  // chunk 7 (ks 28..31): last A prefetch clamped to ks=31, B reads guard region
    const int   wpc = wbaseP + 7 * 2048;
    const int   woc = wbaseO + 7 * 64;
    const char* bc  = bb + 7 * 16384;
    HSTEP(aC0, aC1, bC0, bC1, bC2, bC3, aN0, aN1, bN0, bN1, bN2, bN3, 1 * 512, 1 * 4096)
    HSTEP(aN0, aN1, bN0, bN1, bN2, bN3, aC0, aC1, bC0, bC1, bC2, bC3, 2 * 512, 2 * 4096)
    HSTEP(aC0, aC1, bC0, bC1, bC2, bC3, aN0, aN1, bN0, bN1, bN2, bN3, 3 * 512, 3 * 4096)
    HSTEP(aN0, aN1, bN0, bN1, bN2, bN3, aC0, aC1, bC0, bC1, bC2, bC3, 3 * 512, 4 * 4096)
  }
  store_h32(acc, bias, hbuf, wave, lane);
}

// ---------------- final layer partial: 64 neurons, 8-way wave split ----------------
// wave w: frt=w&3 (32-row quarter), fkh=w>>2 (k half of 256). Both nt in acc.
template<bool BF>
__device__ __forceinline__ void final_partial(
    const uint16_t* __restrict__ wb, const float* __restrict__ wf,
    const uint16_t* hbuf, int frt, int fkh, int lane, f32x16 fa[2]) {
  const int l31 = lane & 31, lh = lane >> 5;
  fa[0] = (f32x16)0.f; fa[1] = (f32x16)0.f;
  const int aP = fkh * 8192 + lh * 256 + l31 * 8;              // + nt*16384 + ks*512
  const int aO = l31 * 512 + fkh * 256 + lh * 8;               // + nt*16384 + ks*16
  const char* fb = (const char*)hbuf + fkh * 65536 + lh * 2048 + (frt * 32 + l31) * 16;
  #pragma unroll 1
  for (int c = 0; c < 4; ++c) {
    #pragma unroll
    for (int j = 0; j < 4; ++j) {
      const int ks = c * 4 + j;
      short8 b  = *(const short8*)(fb + ks * 4096);
      short8 a0 = ldW<BF>(wb, wf, aP + ks * 512,         aO + ks * 16);
      short8 a1 = ldW<BF>(wb, wf, aP + 16384 + ks * 512, aO + 16384 + ks * 16);
      fa[0] = MFMA32(a0, b, fa[0]);
      fa[1] = MFMA32(a1, b, fa[1]);
    }
  }
}

// ---------------- fused coupling kernel: 128 rows/block, 8 waves, 1 block/CU ----------------
template<bool BF>
__global__ __launch_bounds__(512, 2) void coupling(
    const float* __restrict__ z,
    const float* __restrict__ sWin, const float* __restrict__ sbin,
    const float* __restrict__ sWhid, const float* __restrict__ sbhid,
    const float* __restrict__ sWout, const float* __restrict__ sbout,
    const float* __restrict__ tWin, const float* __restrict__ tbin,
    const float* __restrict__ tWhid, const float* __restrict__ tbhid,
    const float* __restrict__ tWout, const float* __restrict__ tbout,
    const uint16_t* __restrict__ wbf, float* __restrict__ out) {
  extern __shared__ __align__(16) uint16_t h[];     // 128KB k-major h + guard
  const int tid = threadIdx.x;
  const int wave = tid >> 6, lane = tid & 63;
  const int l31 = lane & 31, lh = lane >> 5;
  const long rowbase = (long)blockIdx.x * RPB;
  const int frt = wave & 3, fkh = wave >> 2;

  // ---------------- s MLP ----------------
  dense_in<BF>(wbf + OFF_S_WIN, sWin, sbin, z, rowbase, h, wave, lane);
  dense_relu512<BF>(wbf + OFF_S_WHID, sWhid, sbhid, h, wave, lane);
  dense_relu512<BF>(wbf + OFF_S_WHID + 262144, sWhid + 262144, sbhid + 512, h, wave, lane);

  // z1 passthrough copy (all waves; independent of h)
  #pragma unroll
  for (int i = 0; i < 4; ++i) {
    int v = tid + i * 512;
    int row = v >> 4, kc = (v & 15) * 4;
    *(f32x4*)(out + (rowbase + row) * 128 + kc) =
        *(const f32x4*)(z + (rowbase + row) * 128 + kc);
  }

  // ---- s final: 8-way partials + LDS reduce + clip/stash/logdet ----
  {
    f32x16 fa[2];
    final_partial<BF>(wbf + OFF_S_WOUT, sWout, h, frt, fkh, lane, fa);
    __syncthreads();                 // all reads of h done; scratch area reusable
    char* sc = (char*)h + frt * 8192 + lane * 128;
    if (fkh) {
      #pragma unroll
      for (int nt = 0; nt < 2; ++nt)
        #pragma unroll
        for (int q = 0; q < 4; ++q)
          *(f32x4*)(sc + nt * 64 + q * 16) =
              (f32x4){fa[nt][q * 4], fa[nt][q * 4 + 1], fa[nt][q * 4 + 2], fa[nt][q * 4 + 3]};
    }
    __syncthreads();
    if (!fkh) {
      const long row = rowbase + frt * 32 + l31;
      float sum = 0.f;
      #pragma unroll
      for (int nt = 0; nt < 2; ++nt) {
        #pragma unroll
        for (int q = 0; q < 4; ++q) {
          f32x4 p = *(const f32x4*)(sc + nt * 64 + q * 16);
          const int m0 = nt * 32 + q * 8 + lh * 4;
          f32x4 bv = *(const f32x4*)(sbout + m0);
          f32x4 v;
          v.x = fminf(fmaxf(fa[nt][q * 4 + 0] + p.x + bv.x, -2.f), 2.f);
          v.y = fminf(fmaxf(fa[nt][q * 4 + 1] + p.y + bv.y, -2.f), 2.f);
          v.z = fminf(fmaxf(fa[nt][q * 4 + 2] + p.z + bv.z, -2.f), 2.f);
          v.w = fminf(fmaxf(fa[nt][q * 4 + 3] + p.w + bv.w, -2.f), 2.f);
          sum += v.x + v.y + v.z + v.w;
          *(f32x4*)(out + row * 128 + 64 + m0) = v;   // stash log_s
        }
      }
      sum += __shfl_xor(sum, 32, 64);                 // combine lh col-halves
      if (lane < 32) out[(long)NROWS * 128 + row] = sum;   // log_det
    }
  }
  __syncthreads();

  // ---------------- t MLP ----------------
  dense_in<BF>(wbf + OFF_T_WIN, tWin, tbin, z, rowbase, h, wave, lane);
  dense_relu512<BF>(wbf + OFF_T_WHID, tWhid, tbhid, h, wave, lane);
  dense_relu512<BF>(wbf + OFF_T_WHID + 262144, tWhid + 262144, tbhid + 512, h, wave, lane);

  // ---- t final: 8-way partials + LDS reduce + z2 combine ----
  {
    f32x16 fa[2];
    final_partial<BF>(wbf + OFF_T_WOUT, tWout, h, frt, fkh, lane, fa);
    __syncthreads();
    char* sc = (char*)h + frt * 8192 + lane * 128;
    if (fkh) {
      #pragma unroll
      for (int nt = 0; nt < 2; ++nt)
        #pragma unroll
        for (int q = 0; q < 4; ++q)
          *(f32x4*)(sc + nt * 64 + q * 16) =
              (f32x4){fa[nt][q * 4], fa[nt][q * 4 + 1], fa[nt][q * 4 + 2], fa[nt][q * 4 + 3]};
    }
    __syncthreads();
    if (!fkh) {
      const long row = rowbase + frt * 32 + l31;
      #pragma unroll
      for (int nt = 0; nt < 2; ++nt) {
        #pragma unroll
        for (int q = 0; q < 4; ++q) {
          f32x4 p = *(const f32x4*)(sc + nt * 64 + q * 16);
          const int m0 = nt * 32 + q * 8 + lh * 4;
          f32x4 bv = *(const f32x4*)(tbout + m0);
          f32x4 tv;
          tv.x = fa[nt][q * 4 + 0] + p.x + bv.x;
          tv.y = fa[nt][q * 4 + 1] + p.y + bv.y;
          tv.z = fa[nt][q * 4 + 2] + p.z + bv.z;
          tv.w = fa[nt][q * 4 + 3] + p.w + bv.w;
          const long o = row * 128 + 64 + m0;
          f32x4 ls = *(const f32x4*)(out + o);   // log_s stashed by s-phase (same thread)
          f32x4 z2 = *(const f32x4*)(z + o);
          f32x4 r;
          r.x = z2.x * __expf(ls.x) + tv.x;
          r.y = z2.y * __expf(ls.y) + tv.y;
          r.z = z2.z * __expf(ls.z) + tv.z;
          r.w = z2.w * __expf(ls.w) + tv.w;
          *(f32x4*)(out + o) = r;
        }
      }
    }
  }
}

extern "C" void kernel_launch(void* const* d_in, const int* in_sizes, int n_in,
                              void* d_out, int out_size, void* d_ws, size_t ws_size,
                              hipStream_t stream) {
  const float* z     = (const float*)d_in[0];
  const float* sWin  = (const float*)d_in[1];
  const float* sbin  = (const float*)d_in[2];
  const float* sWhid = (const float*)d_in[3];
  const float* sbhid = (const float*)d_in[4];
  const float* sWout = (const float*)d_in[5];
  const float* sbout = (const float*)d_in[6];
  const float* tWin  = (const float*)d_in[7];
  const float* tbin  = (const float*)d_in[8];
  const float* tWhid = (const float*)d_in[9];
  const float* tbhid = (const float*)d_in[10];
  const float* tWout = (const float*)d_in[11];
  const float* tbout = (const float*)d_in[12];
  float* out = (float*)d_out;
  const size_t lds_bytes = 139264;   // 128KB k-major h + prefetch guard (1 block/CU)

  if (ws_size >= (size_t)W_ELEMS * sizeof(uint16_t)) {
    uint16_t* wbf = (uint16_t*)d_ws;
    cvt_weights<<<W_ELEMS / 4 / 256, 256, 0, stream>>>(sWin, sWhid, sWout, tWin, tWhid, tWout, wbf);
    coupling<true><<<NBLK, 512, lds_bytes, stream>>>(z, sWin, sbin, sWhid, sbhid, sWout, sbout,
                                                     tWin, tbin, tWhid, tbhid, tWout, tbout, wbf, out);
  } else {
    coupling<false><<<NBLK, 512, lds_bytes, stream>>>(z, sWin, sbin, sWhid, sbhid, sWout, sbout,
                                                      tWin, tbin, tWhid, tbhid, tWout, tbout,
                                                      (const uint16_t*)d_in[1], out);
  }
}